// Round 9
// baseline (585.695 us; speedup 1.0000x reference)
//
#include <hip/hip_runtime.h>

// ---------------------------------------------------------------------------
// Res_NL pansharpening network, B=1, H=W=128, f32 in/out.
// ONE persistent kernel (256 blocks x 256 threads, provably co-resident:
// VGPR<=256 & LDS 24.2KB -> >=2 blocks/CU capacity >= grid) with a
// sense-reversing device-scope atomic barrier between phases:
//   phase 0 : features (blocks 0..127) + weight prep (blocks 128..255)
//   phase 1 : 3 attention heads (384 LDS tiles, grid-strided)
//   phase 2 : assemble (mlp combine + resu/respan)
//   phase 3+: 7 convs as implicit GEMM on mfma_f32_16x16x32_bf16
// Barrier counters live in ws, zeroed by a hipMemsetAsync graph node.
// ---------------------------------------------------------------------------

#define DEV __device__ __forceinline__
typedef float f32x4 __attribute__((ext_vector_type(4)));
typedef __bf16 bf16x8 __attribute__((ext_vector_type(8)));
typedef unsigned short u16;
typedef unsigned int u32;

constexpr int N = 128 * 128;   // 16384 pixels

// ---- workspace layout (float offsets) -------------------------------------
constexpr int OFF_PHI1 =   0 * N;   // 3 ch
constexpr int OFF_TH1  =   3 * N;   // 3 ch
constexpr int OFF_PHI2 =   6 * N;   // 5 ch
constexpr int OFF_TH2  =  11 * N;   // 5 ch
constexpr int OFF_PHI3 =  16 * N;   // 8 ch
constexpr int OFF_TH3  =  24 * N;   // 8 ch
constexpr int OFF_G1   =  32 * N;   // 5 ch
constexpr int OFF_G2   =  37 * N;   // 5 ch
constexpr int OFF_G3   =  42 * N;   // 5 ch
constexpr int OFF_X    =  47 * N;   // 42 ch f32 (skip path)
constexpr int OFF_OH1  =  89 * N;   // 5 ch
constexpr int OFF_OH2  =  94 * N;   // 5 ch
constexpr int OFF_OH3  =  99 * N;   // 5 ch
constexpr int OFF_XB16 = 110 * N;   // u16[42*N]  x in bf16
constexpr int OFF_FB16 = 131 * N;   // u16[42*N]  f in bf16
constexpr int OFF_SLAB = 152 * N;   // u16[116736] A-layout weights
constexpr int OFF_BTAB = 168 * N;   // u16[384]    B offset table
constexpr int OFF_BAR  = 190 * N;   // u32 cnt @+0, u32 gen @+32 floats
constexpr int SLAB_RB  = 18432;     // per rb conv: 3mt*12ks*64lane*8j
constexpr int SLAB_RC  = 110592;    // recon slab offset
constexpr int SLAB_TOT = 116736;
constexpr u32 NBLK = 256;

DEV bool inb(int y, int x) { return (unsigned)y < 128u && (unsigned)x < 128u; }
DEV u16 f2bf(float f) {
    unsigned u = __float_as_uint(f);
    return (u16)((u + 0x7fffu + ((u >> 16) & 1u)) >> 16);
}

// ---- device-scope sense-reversing global barrier ---------------------------
DEV void gbar(u32* cnt, u32* gen) {
    __syncthreads();
    if (threadIdx.x == 0) {
        __threadfence();   // release: writes visible at device scope
        u32 g = __hip_atomic_load(gen, __ATOMIC_RELAXED, __HIP_MEMORY_SCOPE_AGENT);
        u32 arr = __hip_atomic_fetch_add(cnt, 1u, __ATOMIC_ACQ_REL,
                                         __HIP_MEMORY_SCOPE_AGENT);
        if (arr == NBLK - 1u) {
            __hip_atomic_store(cnt, 0u, __ATOMIC_RELAXED,
                               __HIP_MEMORY_SCOPE_AGENT);
            __hip_atomic_store(gen, g + 1u, __ATOMIC_RELEASE,
                               __HIP_MEMORY_SCOPE_AGENT);
        } else {
            while (__hip_atomic_load(gen, __ATOMIC_ACQUIRE,
                                     __HIP_MEMORY_SCOPE_AGENT) == g)
                __builtin_amdgcn_s_sleep(8);
        }
        __threadfence();   // acquire: drop stale cached lines
    }
    __syncthreads();
}

struct KParams {
    const float* u;    const float* pan;  const float* wnlu; const float* wnlpan;
    const float* gphi; const float* gth;  const float* gg;   const float* sphi;
    const float* sth;  const float* sg;   const float* mphi; const float* mth;
    const float* mg;   const float* mlpw; const float* mlpb; const float* wres;
    const float* wrp;
    const float* wcv[7];     // rb0w1,rb0w2,rb1w1,rb1w2,rb2w1,rb2w2,recon
    const float* bias1[3];
    const float* bias2[3];
    float* ws;
    float* out;
};

// ---------------------------------------------------------------------------
// phase 0a: features. group 0 -> phi2/th2/g1/g2/g3 (uf); group 1 -> phi1/th1
// (pf) + phi3/th3 (uf++pf). uf conv duplicated across groups.
// ---------------------------------------------------------------------------
DEV void features_body(const KParams& kp, int group, int xchunk, int t) {
    float* ws = kp.ws;
    const int p = xchunk * 256 + t;
    const int y = p >> 7, x = p & 127;

    float uv[8][9];
#pragma unroll
    for (int ic = 0; ic < 8; ++ic)
#pragma unroll
        for (int i = 0; i < 3; ++i)
#pragma unroll
            for (int j = 0; j < 3; ++j) {
                int yy = y + i - 1, xx = x + j - 1;
                uv[ic][i * 3 + j] =
                    inb(yy, xx) ? kp.u[ic * N + yy * 128 + xx] : 0.f;
            }

    float uf[5] = {0, 0, 0, 0, 0};
#pragma unroll
    for (int ic = 0; ic < 8; ++ic)
#pragma unroll
        for (int k = 0; k < 9; ++k)
#pragma unroll
            for (int o = 0; o < 5; ++o)
                uf[o] = fmaf(uv[ic][k], kp.wnlu[(o * 8 + ic) * 9 + k], uf[o]);

    if (group == 0) {
#pragma unroll
        for (int o = 0; o < 5; ++o) {
            float a = 0, b = 0, c1 = 0, c2 = 0, c3 = 0;
#pragma unroll
            for (int i = 0; i < 5; ++i) {
                a  = fmaf(kp.sphi[o * 5 + i], uf[i], a);
                b  = fmaf(kp.sth [o * 5 + i], uf[i], b);
                c1 = fmaf(kp.gg  [o * 5 + i], uf[i], c1);
                c2 = fmaf(kp.sg  [o * 5 + i], uf[i], c2);
                c3 = fmaf(kp.mg  [o * 5 + i], uf[i], c3);
            }
            ws[OFF_PHI2 + o * N + p] = a;
            ws[OFF_TH2  + o * N + p] = b;
            ws[OFF_G1   + o * N + p] = c1;
            ws[OFF_G2   + o * N + p] = c2;
            ws[OFF_G3   + o * N + p] = c3;
        }
    } else {
        float pv[9];
#pragma unroll
        for (int i = 0; i < 3; ++i)
#pragma unroll
            for (int j = 0; j < 3; ++j) {
                int yy = y + i - 1, xx = x + j - 1;
                pv[i * 3 + j] = inb(yy, xx) ? kp.pan[yy * 128 + xx] : 0.f;
            }
        float pf[3] = {0, 0, 0};
#pragma unroll
        for (int k = 0; k < 9; ++k)
#pragma unroll
            for (int o = 0; o < 3; ++o)
                pf[o] = fmaf(pv[k], kp.wnlpan[o * 9 + k], pf[o]);

        float cat[8] = {uf[0], uf[1], uf[2], uf[3], uf[4], pf[0], pf[1], pf[2]};
#pragma unroll
        for (int o = 0; o < 3; ++o) {
            float a = 0, b = 0;
#pragma unroll
            for (int i = 0; i < 3; ++i) {
                a = fmaf(kp.gphi[o * 3 + i], pf[i], a);
                b = fmaf(kp.gth [o * 3 + i], pf[i], b);
            }
            ws[OFF_PHI1 + o * N + p] = a;
            ws[OFF_TH1  + o * N + p] = b;
        }
#pragma unroll
        for (int o = 0; o < 8; ++o) {
            float a = 0, b = 0;
#pragma unroll
            for (int i = 0; i < 8; ++i) {
                a = fmaf(kp.mphi[o * 8 + i], cat[i], a);
                b = fmaf(kp.mth [o * 8 + i], cat[i], b);
            }
            ws[OFF_PHI3 + o * N + p] = a;
            ws[OFF_TH3  + o * N + p] = b;
        }
    }
}

// ---------------------------------------------------------------------------
// phase 0b: weight prep -> bf16 MFMA A-layout slabs + B offset table.
// A per lane: A[m = lane&15][k = (lane>>4)*8 + j], k = ic*9 + tau.
// Btab[k] = ic*198 + (tau/3)*66 + (tau%3)
// ---------------------------------------------------------------------------
DEV void wprep_body(const KParams& kp, int wb, int t, u16* slab, u16* btab) {
    for (int idx = wb * 256 + t; idx < 384 + SLAB_TOT; idx += 128 * 256) {
        if (idx < 384) {
            u16 v = 0;
            if (idx < 378) {
                int ic = idx / 9, tau = idx - ic * 9;
                v = (u16)(ic * 198 + (tau / 3) * 66 + (tau % 3));
            }
            btab[idx] = v;
            continue;
        }
        int e = idx - 384;
        const float* W;
        int mt, ks, lane, j, ocv;
        if (e < SLAB_RC) {
            int cv = e / SLAB_RB, r = e - cv * SLAB_RB;
            mt = r / 6144; r -= mt * 6144;
            ks = r / 512;  r -= ks * 512;
            lane = r / 8;  j = r - lane * 8;
            W = kp.wcv[cv]; ocv = 42;
        } else {
            int r = e - SLAB_RC;
            mt = 0;
            ks = r / 512;  r -= ks * 512;
            lane = r / 8;  j = r - lane * 8;
            W = kp.wcv[6]; ocv = 8;
        }
        int k  = ks * 32 + (lane >> 4) * 8 + j;
        int oc = mt * 16 + (lane & 15);
        u16 v = 0;
        if (k < 378 && oc < ocv) {
            int ic = k / 9, tau = k - ic * 9;
            v = f2bf(W[(oc * 42 + ic) * 9 + tau]);
        }
        slab[e] = v;
    }
}

// ---------------------------------------------------------------------------
// phase 1: attention heads, LDS-staged, tile 16x8 px, 2 threads/pixel
// (neighbor-row split), merged via __shfl_xor(.,32).
// ---------------------------------------------------------------------------
template <int C, int P>
DEV void head_tile(const float* __restrict__ phi, const float* __restrict__ theta,
                   const float* __restrict__ g, float* __restrict__ oh,
                   float* __restrict__ smem, int ty0, int tx0, int t) {
    constexpr int PR  = P / 2;
    constexpr int H3  = 3 + PR;
    constexpr int W   = 6 + P;
    constexpr int TTH = 8 + 2 * PR, TTW = 16 + 2 * PR;
    constexpr int PTH = 8 + 2 * H3, PTW = 16 + 2 * H3;
    constexpr int GTH = 14, GTW = 22;

    float* sT = smem;
    float* sP = sT + C * TTH * TTW;
    float* sG = sP + C * PTH * PTW;

    for (int i = t; i < C * TTH * TTW; i += 256) {
        int c = i / (TTH * TTW), rem = i % (TTH * TTW);
        int r = rem / TTW, cc = rem % TTW;
        int gy = ty0 - PR + r, gx = tx0 - PR + cc;
        sT[i] = inb(gy, gx) ? theta[c * N + gy * 128 + gx] : 0.f;
    }
    for (int i = t; i < C * PTH * PTW; i += 256) {
        int c = i / (PTH * PTW), rem = i % (PTH * PTW);
        int r = rem / PTW, cc = rem % PTW;
        int gy = ty0 - H3 + r, gx = tx0 - H3 + cc;
        sP[i] = inb(gy, gx) ? phi[c * N + gy * 128 + gx] : 0.f;
    }
    for (int i = t; i < 5 * GTH * GTW; i += 256) {
        int c = i / (GTH * GTW), rem = i % (GTH * GTW);
        int r = rem / GTW, cc = rem % GTW;
        int gy = ty0 - 3 + r, gx = tx0 - 3 + cc;
        sG[i] = inb(gy, gx) ? g[c * N + gy * 128 + gx] : 0.f;
    }
    __syncthreads();

    const int wave = t >> 6, lane = t & 63, m = lane >> 5;
    const int pidx = (lane & 31) | (wave << 5);
    const int py = pidx >> 4, px = pidx & 15;
    const int gy = ty0 + py, gx = tx0 + px;
    const int dbase = m * 3;

    float s[28];
#pragma unroll
    for (int k = 0; k < 28; ++k) s[k] = 0.f;

    for (int c = 0; c < C; ++c) {
        const float* tc = sT + c * TTH * TTW;
        const float* pc = sP + c * PTH * PTW;
        float T[P][P];
#pragma unroll
        for (int i = 0; i < P; ++i)
#pragma unroll
            for (int j = 0; j < P; ++j)
                T[i][j] = tc[(py + i) * TTW + px + j];
        float R[P][W];
#pragma unroll
        for (int r = 0; r < P; ++r)
#pragma unroll
            for (int w = 0; w < W; ++w)
                R[r][w] = pc[(py + dbase + r) * PTW + px + w];
#pragma unroll
        for (int dd = 0; dd < 4; ++dd) {
#pragma unroll
            for (int dx = 0; dx < 7; ++dx) {
                float a = 0.f;
#pragma unroll
                for (int i = 0; i < P; ++i)
#pragma unroll
                    for (int j = 0; j < P; ++j)
                        a = fmaf(T[i][j], R[i][dx + j], a);
                s[dd * 7 + dx] += a;
            }
            if (dd < 3) {
#pragma unroll
                for (int r = 0; r < P - 1; ++r)
#pragma unroll
                    for (int w = 0; w < W; ++w) R[r][w] = R[r + 1][w];
                int row = py + dbase + dd + P;
#pragma unroll
                for (int w = 0; w < W; ++w)
                    R[P - 1][w] = pc[row * PTW + px + w];
            }
        }
    }
#pragma unroll
    for (int k = 0; k < 28; ++k) {
        int d = dbase + k / 7, dx = k % 7;
        if (!inb(gy + d - 3, gx + dx - 3)) s[k] = 0.f;
    }
    const bool half0 = (m == 0);
    float mx = -3.0e38f;
#pragma unroll
    for (int k = 0; k < 28; ++k) {
        bool own = half0 || (k >= 7);
        mx = own ? fmaxf(mx, s[k]) : mx;
    }
    mx = fmaxf(mx, __shfl_xor(mx, 32));
    float sum = 0.f;
#pragma unroll
    for (int k = 0; k < 28; ++k) {
        bool own = half0 || (k >= 7);
        float e = own ? __expf(s[k] - mx) : 0.f;
        s[k] = e;
        sum += e;
    }
    sum += __shfl_xor(sum, 32);

    float o[5] = {0, 0, 0, 0, 0};
#pragma unroll
    for (int k = 0; k < 28; ++k) {
        int d = dbase + k / 7, dx = k % 7;
        int gr = (py + d) * GTW + px + dx;
#pragma unroll
        for (int c5 = 0; c5 < 5; ++c5)
            o[c5] = fmaf(s[k], sG[c5 * GTH * GTW + gr], o[c5]);
    }
#pragma unroll
    for (int c5 = 0; c5 < 5; ++c5) o[c5] += __shfl_xor(o[c5], 32);

    if (half0) {
        float inv = 1.f / sum;
        int p = gy * 128 + gx;
#pragma unroll
        for (int c5 = 0; c5 < 5; ++c5) oh[c5 * N + p] = o[c5] * inv;
    }
}

// ---------------------------------------------------------------------------
// phase 2: assemble. unit = group*64 + xchunk; writes x f32 AND bf16.
// ---------------------------------------------------------------------------
DEV void assemble_body(const KParams& kp, int unit, int t, u16* xb16) {
    float* ws = kp.ws;
    const int group = unit >> 6;
    const int p = (unit & 63) * 256 + t;
    const int y = p >> 7, x = p & 127;
    float* xb = ws + OFF_X;

    if (group == 0) {
        const float w0 = kp.mlpw[0], w1 = kp.mlpw[1], w2 = kp.mlpw[2];
        const float bb = kp.mlpb[0];
#pragma unroll
        for (int c = 0; c < 5; ++c) {
            float a = ws[OFF_OH1 + c * N + p] * w0 +
                      ws[OFF_OH2 + c * N + p] * w1 +
                      ws[OFF_OH3 + c * N + p] * w2 + bb;
            xb[c * N + p] = a;
            xb16[c * N + p] = f2bf(a);
        }
        float pv[9];
#pragma unroll
        for (int i = 0; i < 3; ++i)
#pragma unroll
            for (int j = 0; j < 3; ++j) {
                int yy = y + i - 1, xx = x + j - 1;
                pv[i * 3 + j] = inb(yy, xx) ? kp.pan[yy * 128 + xx] : 0.f;
            }
        float a5[5] = {0, 0, 0, 0, 0};
#pragma unroll
        for (int k = 0; k < 9; ++k)
#pragma unroll
            for (int o = 0; o < 5; ++o)
                a5[o] = fmaf(pv[k], kp.wrp[o * 9 + k], a5[o]);
#pragma unroll
        for (int o = 0; o < 5; ++o) {
            xb[(37 + o) * N + p] = a5[o];
            xb16[(37 + o) * N + p] = f2bf(a5[o]);
        }
    } else {
        const int ob = (group - 1) * 8;
        float uv[8][9];
#pragma unroll
        for (int ic = 0; ic < 8; ++ic)
#pragma unroll
            for (int i = 0; i < 3; ++i)
#pragma unroll
                for (int j = 0; j < 3; ++j) {
                    int yy = y + i - 1, xx = x + j - 1;
                    uv[ic][i * 3 + j] =
                        inb(yy, xx) ? kp.u[ic * N + yy * 128 + xx] : 0.f;
                }
        float acc[8] = {0, 0, 0, 0, 0, 0, 0, 0};
#pragma unroll
        for (int ic = 0; ic < 8; ++ic)
#pragma unroll
            for (int k = 0; k < 9; ++k)
#pragma unroll
                for (int o = 0; o < 8; ++o)
                    acc[o] = fmaf(uv[ic][k],
                                  kp.wres[((ob + o) * 8 + ic) * 9 + k], acc[o]);
#pragma unroll
        for (int o = 0; o < 8; ++o) {
            xb[(5 + ob + o) * N + p] = acc[o];
            xb16[(5 + ob + o) * N + p] = f2bf(acc[o]);
        }
    }
}

// ---------------------------------------------------------------------------
// phase 3+: implicit-GEMM conv on MFMA. C[42x16384] = W[42x378] * im2col(X).
// Block = 64 consecutive px of one row; 4 waves x 16-px n-tile x MT m-tiles.
// X tile (42ic x 3row x 66col bf16) in LDS; B-frag gathered via offset table;
// A-frags preloaded from slab. D: col=lane&15 (px), row=quad*4+reg (oc).
// ---------------------------------------------------------------------------
template <int MT, int OCV, bool BIAS, bool RELU, bool SKIP, bool WF32, bool WB16>
DEV void conv_body(const u16* __restrict__ xin, const u16* __restrict__ slab,
                   const u16* __restrict__ btab, const float* __restrict__ bs,
                   const float* __restrict__ skip, float* __restrict__ of32,
                   u16* __restrict__ ob16, u16* __restrict__ smu,
                   int bid, int t) {
    u16* sX  = smu;            // 8316 u16
    u16* sBt = smu + 8320;     // 384 u16, 16B-aligned
    const int y = bid >> 1, x0 = (bid & 1) << 6;

    for (int i = t; i < 8316; i += 256) {
        int ic = i / 198, rem = i - ic * 198;
        int r = rem / 66, cc = rem - r * 66;
        int gy = y - 1 + r, gx = x0 - 1 + cc;
        sX[i] = inb(gy, gx) ? xin[ic * N + gy * 128 + gx] : (u16)0;
    }
    for (int i = t; i < 384; i += 256) sBt[i] = btab[i];
    __syncthreads();

    const int lane = t & 63, wave = t >> 6;
    const int quad = lane >> 4, col = lane & 15;
    const int ncol = wave * 16 + col;

    union AB { uint4 u; bf16x8 b; };
    AB a[MT][12];
#pragma unroll
    for (int mt = 0; mt < MT; ++mt)
#pragma unroll
        for (int ks = 0; ks < 12; ++ks)
            a[mt][ks].u = ((const uint4*)slab)[(mt * 12 + ks) * 64 + lane];

    f32x4 acc[MT];
#pragma unroll
    for (int mt = 0; mt < MT; ++mt) acc[mt] = {0.f, 0.f, 0.f, 0.f};

#pragma unroll
    for (int ks = 0; ks < 12; ++ks) {
        union { uint4 u; u16 s[8]; } off;
        off.u = *(const uint4*)(sBt + ks * 32 + quad * 8);
        union { u16 s[8]; bf16x8 b; } bv;
#pragma unroll
        for (int j = 0; j < 8; ++j) bv.s[j] = sX[off.s[j] + ncol];
#pragma unroll
        for (int mt = 0; mt < MT; ++mt)
            acc[mt] = __builtin_amdgcn_mfma_f32_16x16x32_bf16(
                a[mt][ks].b, bv.b, acc[mt], 0, 0, 0);
    }

    const int px = y * 128 + x0 + ncol;
#pragma unroll
    for (int mt = 0; mt < MT; ++mt)
#pragma unroll
        for (int reg = 0; reg < 4; ++reg) {
            int oc = mt * 16 + quad * 4 + reg;
            if (oc < OCV) {
                float v = acc[mt][reg];
                if (BIAS) v += bs[oc];
                if (SKIP) v += skip[oc * N + px];
                if (RELU) v = fmaxf(v, 0.f);
                if (WF32) of32[oc * N + px] = v;
                if (WB16) ob16[oc * N + px] = f2bf(v);
            }
        }
}

// ---------------------------------------------------------------------------
// The persistent mega kernel.
// ---------------------------------------------------------------------------
__global__ __launch_bounds__(256, 2) void mega_k(KParams kp) {
    __shared__ __align__(16) char smem_raw[24208];
    float* smf = (float*)smem_raw;
    u16*   smu = (u16*)smem_raw;

    const int bid = blockIdx.x, t = threadIdx.x;
    float* ws = kp.ws;
    u16* xb16 = (u16*)(ws + OFF_XB16);
    u16* fb16 = (u16*)(ws + OFF_FB16);
    u16* slab = (u16*)(ws + OFF_SLAB);
    u16* btab = (u16*)(ws + OFF_BTAB);
    u32* cnt  = (u32*)(ws + OFF_BAR);
    u32* gen  = (u32*)(ws + OFF_BAR + 32);

    // ---- phase 0: features (0..127) + wprep (128..255) ----
    if (bid < 64)        features_body(kp, 0, bid, t);
    else if (bid < 128)  features_body(kp, 1, bid - 64, t);
    else                 wprep_body(kp, bid - 128, t, slab, btab);
    gbar(cnt, gen);

    // ---- phase 1: heads (384 tiles) ----
    for (int tl = bid; tl < 384; tl += 256) {
        __syncthreads();
        const int head = tl >> 7, tile = tl & 127;
        const int ty0 = (tile >> 3) * 8, tx0 = (tile & 7) * 16;
        if (head == 0)
            head_tile<3, 3>(ws + OFF_PHI1, ws + OFF_TH1, ws + OFF_G1,
                            ws + OFF_OH1, smf, ty0, tx0, t);
        else if (head == 1)
            head_tile<5, 1>(ws + OFF_PHI2, ws + OFF_TH2, ws + OFF_G2,
                            ws + OFF_OH2, smf, ty0, tx0, t);
        else
            head_tile<8, 3>(ws + OFF_PHI3, ws + OFF_TH3, ws + OFF_G3,
                            ws + OFF_OH3, smf, ty0, tx0, t);
    }
    gbar(cnt, gen);

    // ---- phase 2: assemble (320 units) ----
    for (int unit = bid; unit < 320; unit += 256)
        assemble_body(kp, unit, t, xb16);
    gbar(cnt, gen);

    // ---- phase 3+: res blocks (6 convs) + recon ----
    for (int r = 0; r < 3; ++r) {
        conv_body<3, 42, true, true, false, false, true>(
            xb16, slab + (2 * r) * SLAB_RB, btab, kp.bias1[r], nullptr,
            nullptr, fb16, smu, bid, t);
        gbar(cnt, gen);
        conv_body<3, 42, true, true, true, true, true>(
            fb16, slab + (2 * r + 1) * SLAB_RB, btab, kp.bias2[r],
            ws + OFF_X, ws + OFF_X, xb16, smu, bid, t);
        gbar(cnt, gen);
    }
    conv_body<1, 8, false, false, false, true, false>(
        xb16, slab + SLAB_RC, btab, nullptr, nullptr, kp.out, nullptr,
        smu, bid, t);
}

// ---------------------------------------------------------------------------
extern "C" void kernel_launch(void* const* d_in, const int* in_sizes, int n_in,
                              void* d_out, int out_size, void* d_ws, size_t ws_size,
                              hipStream_t stream) {
    (void)in_sizes; (void)n_in; (void)out_size; (void)ws_size;
    KParams kp;
    kp.u      = (const float*)d_in[0];
    kp.pan    = (const float*)d_in[1];
    kp.wnlu   = (const float*)d_in[2];
    kp.wnlpan = (const float*)d_in[3];
    kp.gphi   = (const float*)d_in[4];
    kp.gth    = (const float*)d_in[5];
    kp.gg     = (const float*)d_in[6];
    kp.sphi   = (const float*)d_in[7];
    kp.sth    = (const float*)d_in[8];
    kp.sg     = (const float*)d_in[9];
    kp.mphi   = (const float*)d_in[10];
    kp.mth    = (const float*)d_in[11];
    kp.mg     = (const float*)d_in[12];
    kp.mlpw   = (const float*)d_in[13];
    kp.mlpb   = (const float*)d_in[14];
    kp.wres   = (const float*)d_in[15];
    kp.wrp    = (const float*)d_in[16];
    kp.wcv[0] = (const float*)d_in[18];
    kp.wcv[1] = (const float*)d_in[20];
    kp.wcv[2] = (const float*)d_in[22];
    kp.wcv[3] = (const float*)d_in[24];
    kp.wcv[4] = (const float*)d_in[26];
    kp.wcv[5] = (const float*)d_in[28];
    kp.wcv[6] = (const float*)d_in[17];   // recon
    kp.bias1[0] = (const float*)d_in[19];
    kp.bias1[1] = (const float*)d_in[23];
    kp.bias1[2] = (const float*)d_in[27];
    kp.bias2[0] = (const float*)d_in[21];
    kp.bias2[1] = (const float*)d_in[25];
    kp.bias2[2] = (const float*)d_in[29];
    kp.ws  = (float*)d_ws;
    kp.out = (float*)d_out;

    // zero the barrier counters (cnt @ OFF_BAR, gen @ OFF_BAR+32 floats)
    hipMemsetAsync((char*)d_ws + (size_t)OFF_BAR * 4, 0, 256, stream);
    mega_k<<<NBLK, 256, 0, stream>>>(kp);
}

// Round 10
// 210.474 us; speedup vs baseline: 2.7827x; 2.7827x over previous
//
#include <hip/hip_runtime.h>

// ---------------------------------------------------------------------------
// Res_NL pansharpening network, B=1, H=W=128, f32 in/out. Multi-kernel
// (launch overhead measured ~2us; persistent-kernel barriers cost more).
//   features_k : uf/pf 3x3 convs + nine 1x1 transforms
//   heads_k    : 3 attention heads, LDS-staged (unrolled staging)
//   wprep_k    : bf16 MFMA A-slabs + B offset table + padded-border zeroing
//   assemble_k : mlp combine + resu/respan; writes x f32 + PADDED bf16
//   convm_k    : implicit-GEMM conv on mfma_f32_16x16x32_bf16, activations in
//                halo-padded bf16 [42][130][136] -> vectorized maskless staging
// ---------------------------------------------------------------------------

#define DEV __device__ __forceinline__
typedef float f32x4 __attribute__((ext_vector_type(4)));
typedef __bf16 bf16x8 __attribute__((ext_vector_type(8)));
typedef unsigned short u16;
typedef unsigned int u32;

constexpr int N = 128 * 128;   // 16384 pixels

// ---- workspace layout (float offsets) -------------------------------------
constexpr int OFF_PHI1 =   0 * N;   // 3 ch
constexpr int OFF_TH1  =   3 * N;   // 3 ch
constexpr int OFF_PHI2 =   6 * N;   // 5 ch
constexpr int OFF_TH2  =  11 * N;   // 5 ch
constexpr int OFF_PHI3 =  16 * N;   // 8 ch
constexpr int OFF_TH3  =  24 * N;   // 8 ch
constexpr int OFF_G1   =  32 * N;   // 5 ch
constexpr int OFF_G2   =  37 * N;   // 5 ch
constexpr int OFF_G3   =  42 * N;   // 5 ch
constexpr int OFF_X    =  47 * N;   // 42 ch f32 (skip path)
constexpr int OFF_OH1  =  89 * N;   // 5 ch
constexpr int OFF_OH2  =  94 * N;   // 5 ch
constexpr int OFF_OH3  =  99 * N;   // 5 ch
// padded bf16 activations: [42][130][136] u16, element (ic,y,x) at
// ic*17680 + (y+1)*136 + (x+1); borders zero.
constexpr int XPLANE   = 130 * 136;           // 17680 u16
constexpr int OFF_XPAD = 110 * N;             // 742560 u16 = 22.7N floats
constexpr int OFF_FPAD = 133 * N;
constexpr int OFF_SLAB = 156 * N;             // u16[116736]
constexpr int OFF_BTAB = 160 * N;             // u16[384]
constexpr int SLAB_RB  = 18432;               // per rb conv
constexpr int SLAB_RC  = 110592;              // recon slab offset
constexpr int SLAB_TOT = 116736;
constexpr int ZPB      = 528;                 // border u16 per plane
constexpr int ZTOT     = 2 * 42 * ZPB;        // both buffers
constexpr int WPREP_TOT = 384 + SLAB_TOT + ZTOT;

DEV bool inb(int y, int x) { return (unsigned)y < 128u && (unsigned)x < 128u; }
DEV u16 f2bf(float f) {
    unsigned u = __float_as_uint(f);
    return (u16)((u + 0x7fffu + ((u >> 16) & 1u)) >> 16);
}

// ---------------------------------------------------------------------------
// K1: features. grid (64, 2). Group 0 writes phi2/th2/g1/g2/g3 (uf only);
// group 1 writes phi1/th1 (pf) and phi3/th3 (uf++pf). uf conv duplicated.
// ---------------------------------------------------------------------------
__global__ __launch_bounds__(256, 2) void features_k(
    const float* __restrict__ u, const float* __restrict__ pan,
    const float* __restrict__ wnlu, const float* __restrict__ wnlpan,
    const float* __restrict__ gphi, const float* __restrict__ gth,
    const float* __restrict__ gg, const float* __restrict__ sphi,
    const float* __restrict__ sth, const float* __restrict__ sg,
    const float* __restrict__ mphi, const float* __restrict__ mth,
    const float* __restrict__ mg, float* __restrict__ ws) {
    const int p = blockIdx.x * 256 + threadIdx.x;
    const int y = p >> 7, x = p & 127;

    float uv[8][9];
#pragma unroll
    for (int ic = 0; ic < 8; ++ic)
#pragma unroll
        for (int i = 0; i < 3; ++i)
#pragma unroll
            for (int j = 0; j < 3; ++j) {
                int yy = y + i - 1, xx = x + j - 1;
                uv[ic][i * 3 + j] = inb(yy, xx) ? u[ic * N + yy * 128 + xx] : 0.f;
            }

    float uf[5] = {0, 0, 0, 0, 0};
#pragma unroll
    for (int ic = 0; ic < 8; ++ic)
#pragma unroll
        for (int k = 0; k < 9; ++k)
#pragma unroll
            for (int o = 0; o < 5; ++o)
                uf[o] = fmaf(uv[ic][k], wnlu[(o * 8 + ic) * 9 + k], uf[o]);

    if (blockIdx.y == 0) {
#pragma unroll
        for (int o = 0; o < 5; ++o) {
            float a = 0, b = 0, c1 = 0, c2 = 0, c3 = 0;
#pragma unroll
            for (int i = 0; i < 5; ++i) {
                a  = fmaf(sphi[o * 5 + i], uf[i], a);
                b  = fmaf(sth [o * 5 + i], uf[i], b);
                c1 = fmaf(gg  [o * 5 + i], uf[i], c1);
                c2 = fmaf(sg  [o * 5 + i], uf[i], c2);
                c3 = fmaf(mg  [o * 5 + i], uf[i], c3);
            }
            ws[OFF_PHI2 + o * N + p] = a;
            ws[OFF_TH2  + o * N + p] = b;
            ws[OFF_G1   + o * N + p] = c1;
            ws[OFF_G2   + o * N + p] = c2;
            ws[OFF_G3   + o * N + p] = c3;
        }
    } else {
        float pv[9];
#pragma unroll
        for (int i = 0; i < 3; ++i)
#pragma unroll
            for (int j = 0; j < 3; ++j) {
                int yy = y + i - 1, xx = x + j - 1;
                pv[i * 3 + j] = inb(yy, xx) ? pan[yy * 128 + xx] : 0.f;
            }
        float pf[3] = {0, 0, 0};
#pragma unroll
        for (int k = 0; k < 9; ++k)
#pragma unroll
            for (int o = 0; o < 3; ++o)
                pf[o] = fmaf(pv[k], wnlpan[o * 9 + k], pf[o]);

        float cat[8] = {uf[0], uf[1], uf[2], uf[3], uf[4], pf[0], pf[1], pf[2]};
#pragma unroll
        for (int o = 0; o < 3; ++o) {
            float a = 0, b = 0;
#pragma unroll
            for (int i = 0; i < 3; ++i) {
                a = fmaf(gphi[o * 3 + i], pf[i], a);
                b = fmaf(gth [o * 3 + i], pf[i], b);
            }
            ws[OFF_PHI1 + o * N + p] = a;
            ws[OFF_TH1  + o * N + p] = b;
        }
#pragma unroll
        for (int o = 0; o < 8; ++o) {
            float a = 0, b = 0;
#pragma unroll
            for (int i = 0; i < 8; ++i) {
                a = fmaf(mphi[o * 8 + i], cat[i], a);
                b = fmaf(mth [o * 8 + i], cat[i], b);
            }
            ws[OFF_PHI3 + o * N + p] = a;
            ws[OFF_TH3  + o * N + p] = b;
        }
    }
}

// ---------------------------------------------------------------------------
// K2: attention heads. Staging loops fully unrolled (compile-time trips) so
// the ~30 independent global loads batch into one vmcnt window.
// ---------------------------------------------------------------------------
template <int C, int P>
DEV void head_tile(const float* __restrict__ phi, const float* __restrict__ theta,
                   const float* __restrict__ g, float* __restrict__ oh,
                   float* __restrict__ smem, int ty0, int tx0, int t) {
    constexpr int PR  = P / 2;
    constexpr int H3  = 3 + PR;
    constexpr int W   = 6 + P;
    constexpr int TTH = 8 + 2 * PR, TTW = 16 + 2 * PR;
    constexpr int PTH = 8 + 2 * H3, PTW = 16 + 2 * H3;
    constexpr int GTH = 14, GTW = 22;

    float* sT = smem;
    float* sP = sT + C * TTH * TTW;
    float* sG = sP + C * PTH * PTW;

#pragma unroll
    for (int c = 0; c < C; ++c)
#pragma unroll
        for (int base = 0; base < TTH * TTW; base += 256) {
            int i = base + t;
            if (i < TTH * TTW) {
                int r = i / TTW, cc = i - r * TTW;
                int gy = ty0 - PR + r, gx = tx0 - PR + cc;
                sT[c * TTH * TTW + i] =
                    inb(gy, gx) ? theta[c * N + gy * 128 + gx] : 0.f;
            }
        }
#pragma unroll
    for (int c = 0; c < C; ++c)
#pragma unroll
        for (int base = 0; base < PTH * PTW; base += 256) {
            int i = base + t;
            if (i < PTH * PTW) {
                int r = i / PTW, cc = i - r * PTW;
                int gy = ty0 - H3 + r, gx = tx0 - H3 + cc;
                sP[c * PTH * PTW + i] =
                    inb(gy, gx) ? phi[c * N + gy * 128 + gx] : 0.f;
            }
        }
#pragma unroll
    for (int c = 0; c < 5; ++c)
#pragma unroll
        for (int base = 0; base < GTH * GTW; base += 256) {
            int i = base + t;
            if (i < GTH * GTW) {
                int r = i / GTW, cc = i - r * GTW;
                int gy = ty0 - 3 + r, gx = tx0 - 3 + cc;
                sG[c * GTH * GTW + i] =
                    inb(gy, gx) ? g[c * N + gy * 128 + gx] : 0.f;
            }
        }
    __syncthreads();

    const int wave = t >> 6, lane = t & 63, m = lane >> 5;
    const int pidx = (lane & 31) | (wave << 5);
    const int py = pidx >> 4, px = pidx & 15;
    const int gy = ty0 + py, gx = tx0 + px;
    const int dbase = m * 3;

    float s[28];
#pragma unroll
    for (int k = 0; k < 28; ++k) s[k] = 0.f;

    for (int c = 0; c < C; ++c) {
        const float* tc = sT + c * TTH * TTW;
        const float* pc = sP + c * PTH * PTW;
        float T[P][P];
#pragma unroll
        for (int i = 0; i < P; ++i)
#pragma unroll
            for (int j = 0; j < P; ++j)
                T[i][j] = tc[(py + i) * TTW + px + j];
        float R[P][W];
#pragma unroll
        for (int r = 0; r < P; ++r)
#pragma unroll
            for (int w = 0; w < W; ++w)
                R[r][w] = pc[(py + dbase + r) * PTW + px + w];
#pragma unroll
        for (int dd = 0; dd < 4; ++dd) {
#pragma unroll
            for (int dx = 0; dx < 7; ++dx) {
                float a = 0.f;
#pragma unroll
                for (int i = 0; i < P; ++i)
#pragma unroll
                    for (int j = 0; j < P; ++j)
                        a = fmaf(T[i][j], R[i][dx + j], a);
                s[dd * 7 + dx] += a;
            }
            if (dd < 3) {
#pragma unroll
                for (int r = 0; r < P - 1; ++r)
#pragma unroll
                    for (int w = 0; w < W; ++w) R[r][w] = R[r + 1][w];
                int row = py + dbase + dd + P;
#pragma unroll
                for (int w = 0; w < W; ++w)
                    R[P - 1][w] = pc[row * PTW + px + w];
            }
        }
    }
#pragma unroll
    for (int k = 0; k < 28; ++k) {
        int d = dbase + k / 7, dx = k % 7;
        if (!inb(gy + d - 3, gx + dx - 3)) s[k] = 0.f;
    }
    const bool half0 = (m == 0);
    float mx = -3.0e38f;
#pragma unroll
    for (int k = 0; k < 28; ++k) {
        bool own = half0 || (k >= 7);
        mx = own ? fmaxf(mx, s[k]) : mx;
    }
    mx = fmaxf(mx, __shfl_xor(mx, 32));
    float sum = 0.f;
#pragma unroll
    for (int k = 0; k < 28; ++k) {
        bool own = half0 || (k >= 7);
        float e = own ? __expf(s[k] - mx) : 0.f;
        s[k] = e;
        sum += e;
    }
    sum += __shfl_xor(sum, 32);

    float o[5] = {0, 0, 0, 0, 0};
#pragma unroll
    for (int k = 0; k < 28; ++k) {
        int d = dbase + k / 7, dx = k % 7;
        int gr = (py + d) * GTW + px + dx;
#pragma unroll
        for (int c5 = 0; c5 < 5; ++c5)
            o[c5] = fmaf(s[k], sG[c5 * GTH * GTW + gr], o[c5]);
    }
#pragma unroll
    for (int c5 = 0; c5 < 5; ++c5) o[c5] += __shfl_xor(o[c5], 32);

    if (half0) {
        float inv = 1.f / sum;
        int p = gy * 128 + gx;
#pragma unroll
        for (int c5 = 0; c5 < 5; ++c5) oh[c5 * N + p] = o[c5] * inv;
    }
}

__global__ __launch_bounds__(256) void heads_k(float* __restrict__ ws) {
    __shared__ float smem[6052];
    const int t = threadIdx.x;
    const int ty0 = (blockIdx.x >> 3) * 8, tx0 = (blockIdx.x & 7) * 16;
    if (blockIdx.y == 0)
        head_tile<3, 3>(ws + OFF_PHI1, ws + OFF_TH1, ws + OFF_G1, ws + OFF_OH1,
                        smem, ty0, tx0, t);
    else if (blockIdx.y == 1)
        head_tile<5, 1>(ws + OFF_PHI2, ws + OFF_TH2, ws + OFF_G2, ws + OFF_OH2,
                        smem, ty0, tx0, t);
    else
        head_tile<8, 3>(ws + OFF_PHI3, ws + OFF_TH3, ws + OFF_G3, ws + OFF_OH3,
                        smem, ty0, tx0, t);
}

// ---------------------------------------------------------------------------
// K2b: weight prep. (a) bf16 A-layout slabs: lane holds A[m=lane&15]
// [k=(lane>>4)*8+j], k=ic*9+tau; (b) B offset table for padded LDS tile
// (row stride 72): btab[k] = ic*216 + (tau/3)*72 + tau%3; (c) zero the
// halo borders of XPAD and FPAD (528 u16 per plane: rows 0/129 full,
// cols 0 and 129 of rows 1..128).
// ---------------------------------------------------------------------------
struct WPtrs { const float* w[7]; };   // rb0w1,rb0w2,rb1w1,rb1w2,rb2w1,rb2w2,recon

__global__ __launch_bounds__(256) void wprep_k(WPtrs wp, u16* __restrict__ slab,
                                               u16* __restrict__ btab,
                                               u16* __restrict__ xpad,
                                               u16* __restrict__ fpad) {
    int idx = blockIdx.x * 256 + threadIdx.x;
    if (idx >= WPREP_TOT) return;
    if (idx < 384) {
        u16 v = 0;
        if (idx < 378) {
            int ic = idx / 9, tau = idx - ic * 9;
            v = (u16)(ic * 216 + (tau / 3) * 72 + (tau % 3));
        }
        btab[idx] = v;
        return;
    }
    idx -= 384;
    if (idx < SLAB_TOT) {
        const float* W;
        int mt, ks, lane, j, ocv;
        if (idx < SLAB_RC) {
            int cv = idx / SLAB_RB, r = idx - cv * SLAB_RB;
            mt = r / 6144; r -= mt * 6144;
            ks = r / 512;  r -= ks * 512;
            lane = r / 8;  j = r - lane * 8;
            W = wp.w[cv]; ocv = 42;
        } else {
            int r = idx - SLAB_RC;
            mt = 0;
            ks = r / 512;  r -= ks * 512;
            lane = r / 8;  j = r - lane * 8;
            W = wp.w[6]; ocv = 8;
        }
        int k  = ks * 32 + (lane >> 4) * 8 + j;
        int oc = mt * 16 + (lane & 15);
        u16 v = 0;
        if (k < 378 && oc < ocv) {
            int ic = k / 9, tau = k - ic * 9;
            v = f2bf(W[(oc * 42 + ic) * 9 + tau]);
        }
        slab[idx] = v;
        return;
    }
    idx -= SLAB_TOT;
    u16* buf = (idx < 42 * ZPB) ? xpad : fpad;
    int e = (idx < 42 * ZPB) ? idx : idx - 42 * ZPB;
    int plane = e / ZPB, rem = e - plane * ZPB;
    int row, col;
    if (rem < 136)      { row = 0;             col = rem; }
    else if (rem < 272) { row = 129;           col = rem - 136; }
    else if (rem < 400) { row = 1 + rem - 272; col = 0; }
    else                { row = 1 + rem - 400; col = 129; }
    buf[plane * XPLANE + row * 136 + col] = 0;
}

// ---------------------------------------------------------------------------
// K3: assemble, grid (64, 5). Writes x f32 (skip) + padded bf16 (MFMA input).
// ---------------------------------------------------------------------------
__global__ __launch_bounds__(256, 2) void assemble_k(
    const float* __restrict__ u, const float* __restrict__ pan,
    const float* __restrict__ wres, const float* __restrict__ wrp,
    const float* __restrict__ mlpw, const float* __restrict__ mlpb,
    float* __restrict__ ws, u16* __restrict__ xpad) {
    const int p = blockIdx.x * 256 + threadIdx.x;
    const int y = p >> 7, x = p & 127;
    const int padp = (y + 1) * 136 + (x + 1);
    float* xb = ws + OFF_X;

    if (blockIdx.y == 0) {
        const float w0 = mlpw[0], w1 = mlpw[1], w2 = mlpw[2];
        const float bb = mlpb[0];
#pragma unroll
        for (int c = 0; c < 5; ++c) {
            float a = ws[OFF_OH1 + c * N + p] * w0 +
                      ws[OFF_OH2 + c * N + p] * w1 +
                      ws[OFF_OH3 + c * N + p] * w2 + bb;
            xb[c * N + p] = a;
            xpad[c * XPLANE + padp] = f2bf(a);
        }
        float pv[9];
#pragma unroll
        for (int i = 0; i < 3; ++i)
#pragma unroll
            for (int j = 0; j < 3; ++j) {
                int yy = y + i - 1, xx = x + j - 1;
                pv[i * 3 + j] = inb(yy, xx) ? pan[yy * 128 + xx] : 0.f;
            }
        float a5[5] = {0, 0, 0, 0, 0};
#pragma unroll
        for (int k = 0; k < 9; ++k)
#pragma unroll
            for (int o = 0; o < 5; ++o)
                a5[o] = fmaf(pv[k], wrp[o * 9 + k], a5[o]);
#pragma unroll
        for (int o = 0; o < 5; ++o) {
            xb[(37 + o) * N + p] = a5[o];
            xpad[(37 + o) * XPLANE + padp] = f2bf(a5[o]);
        }
    } else {
        const int ob = (blockIdx.y - 1) * 8;
        float uv[8][9];
#pragma unroll
        for (int ic = 0; ic < 8; ++ic)
#pragma unroll
            for (int i = 0; i < 3; ++i)
#pragma unroll
                for (int j = 0; j < 3; ++j) {
                    int yy = y + i - 1, xx = x + j - 1;
                    uv[ic][i * 3 + j] =
                        inb(yy, xx) ? u[ic * N + yy * 128 + xx] : 0.f;
                }
        float acc[8] = {0, 0, 0, 0, 0, 0, 0, 0};
#pragma unroll
        for (int ic = 0; ic < 8; ++ic)
#pragma unroll
            for (int k = 0; k < 9; ++k)
#pragma unroll
                for (int o = 0; o < 8; ++o)
                    acc[o] = fmaf(uv[ic][k], wres[((ob + o) * 8 + ic) * 9 + k],
                                  acc[o]);
#pragma unroll
        for (int o = 0; o < 8; ++o) {
            xb[(5 + ob + o) * N + p] = acc[o];
            xpad[(5 + ob + o) * XPLANE + padp] = f2bf(acc[o]);
        }
    }
}

// ---------------------------------------------------------------------------
// K4: implicit-GEMM conv on MFMA, padded bf16 input. Block = 64 px of one
// row (grid 256). Staging: 126 tile rows x (8 x uint4 + 1 x u32), fully
// unrolled, maskless (halo handled by padding). LDS row stride 72 u16.
// D layout: col=lane&15 (px), row=quad*4+reg (oc).
// ---------------------------------------------------------------------------
template <int MT, int OCV, bool BIAS, bool RELU, bool SKIP, bool WF32, bool WPAD>
__global__ __launch_bounds__(256, 1) void convm_k(
    const u16* __restrict__ xin, const u16* __restrict__ slab,
    const u16* __restrict__ btab, const float* __restrict__ bs,
    const float* __restrict__ skip, float* __restrict__ of32,
    u16* __restrict__ opad) {
    __shared__ __align__(16) u16 sX[9072];    // 42*3*72
    __shared__ __align__(16) u16 sBt[384];
    const int t = threadIdx.x;
    const int y = blockIdx.x >> 1, x0 = (blockIdx.x & 1) << 6;

    const u16* srcbase = xin + y * 136 + x0;   // 16B-aligned
#pragma unroll
    for (int it = 0; it < 4; ++it) {
        int c = it * 256 + t;
        if (c < 1008) {                        // 126 rows * 8 slots
            int row = c >> 3, slot = c & 7;
            int ic = row / 3, r = row - ic * 3;
            uint4 v = *((const uint4*)(srcbase + ic * XPLANE + r * 136) + slot);
            *(uint4*)(sX + row * 72 + slot * 8) = v;
        }
    }
    if (t < 126) {
        int ic = t / 3, r = t - ic * 3;
        u32 v = *(const u32*)(srcbase + ic * XPLANE + r * 136 + 64);
        *(u32*)(sX + t * 72 + 64) = v;
    }
    for (int i = t; i < 384; i += 256) sBt[i] = btab[i];
    __syncthreads();

    const int lane = t & 63, wave = t >> 6;
    const int quad = lane >> 4, col = lane & 15;
    const int ncol = wave * 16 + col;

    union AB { uint4 u; bf16x8 b; };
    AB a[MT][12];
#pragma unroll
    for (int mt = 0; mt < MT; ++mt)
#pragma unroll
        for (int ks = 0; ks < 12; ++ks)
            a[mt][ks].u = ((const uint4*)slab)[(mt * 12 + ks) * 64 + lane];

    f32x4 acc[MT];
#pragma unroll
    for (int mt = 0; mt < MT; ++mt) acc[mt] = {0.f, 0.f, 0.f, 0.f};

#pragma unroll
    for (int ks = 0; ks < 12; ++ks) {
        union { uint4 u; u16 s[8]; } off;
        off.u = *(const uint4*)(sBt + ks * 32 + quad * 8);
        union { u16 s[8]; bf16x8 b; } bv;
#pragma unroll
        for (int j = 0; j < 8; ++j) bv.s[j] = sX[off.s[j] + ncol];
#pragma unroll
        for (int mt = 0; mt < MT; ++mt)
            acc[mt] = __builtin_amdgcn_mfma_f32_16x16x32_bf16(
                a[mt][ks].b, bv.b, acc[mt], 0, 0, 0);
    }

    const int xg = x0 + ncol;
    const int px = y * 128 + xg;
    const int padp = (y + 1) * 136 + (xg + 1);
#pragma unroll
    for (int mt = 0; mt < MT; ++mt)
#pragma unroll
        for (int reg = 0; reg < 4; ++reg) {
            int oc = mt * 16 + quad * 4 + reg;
            if (oc < OCV) {
                float v = acc[mt][reg];
                if (BIAS) v += bs[oc];
                if (SKIP) v += skip[oc * N + px];
                if (RELU) v = fmaxf(v, 0.f);
                if (WF32) of32[oc * N + px] = v;
                if (WPAD) opad[oc * XPLANE + padp] = f2bf(v);
            }
        }
}

// ---------------------------------------------------------------------------
extern "C" void kernel_launch(void* const* d_in, const int* in_sizes, int n_in,
                              void* d_out, int out_size, void* d_ws, size_t ws_size,
                              hipStream_t stream) {
    (void)in_sizes; (void)n_in; (void)out_size; (void)ws_size;
    float* ws = (float*)d_ws;
    float* out = (float*)d_out;

    const float* u      = (const float*)d_in[0];
    const float* pan    = (const float*)d_in[1];
    const float* wnlu   = (const float*)d_in[2];
    const float* wnlpan = (const float*)d_in[3];
    const float* gphi   = (const float*)d_in[4];
    const float* gth    = (const float*)d_in[5];
    const float* gg     = (const float*)d_in[6];
    const float* sphi   = (const float*)d_in[7];
    const float* sth    = (const float*)d_in[8];
    const float* sg     = (const float*)d_in[9];
    const float* mphi   = (const float*)d_in[10];
    const float* mth    = (const float*)d_in[11];
    const float* mg     = (const float*)d_in[12];
    const float* mlpw   = (const float*)d_in[13];
    const float* mlpb   = (const float*)d_in[14];
    const float* wres   = (const float*)d_in[15];
    const float* wrp    = (const float*)d_in[16];
    const float* wrecon = (const float*)d_in[17];

    u16* xpad = (u16*)(ws + OFF_XPAD);
    u16* fpad = (u16*)(ws + OFF_FPAD);
    u16* slab = (u16*)(ws + OFF_SLAB);
    u16* btab = (u16*)(ws + OFF_BTAB);

    features_k<<<dim3(N / 256, 2), 256, 0, stream>>>(
        u, pan, wnlu, wnlpan, gphi, gth, gg, sphi, sth, sg, mphi, mth, mg, ws);
    heads_k<<<dim3(128, 3), 256, 0, stream>>>(ws);

    WPtrs wp;
    wp.w[0] = (const float*)d_in[18]; wp.w[1] = (const float*)d_in[20];
    wp.w[2] = (const float*)d_in[22]; wp.w[3] = (const float*)d_in[24];
    wp.w[4] = (const float*)d_in[26]; wp.w[5] = (const float*)d_in[28];
    wp.w[6] = wrecon;
    wprep_k<<<(WPREP_TOT + 255) / 256, 256, 0, stream>>>(wp, slab, btab,
                                                         xpad, fpad);

    assemble_k<<<dim3(N / 256, 5), 256, 0, stream>>>(u, pan, wres, wrp, mlpw,
                                                     mlpb, ws, xpad);

    for (int r = 0; r < 3; ++r) {
        const float* b1 = (const float*)d_in[19 + 4 * r];
        const float* b2 = (const float*)d_in[21 + 4 * r];
        // f = relu(conv(x,w1)+b1): padded bf16 out only
        convm_k<3, 42, true, true, false, false, true>
            <<<256, 256, 0, stream>>>(xpad, slab + (2 * r) * SLAB_RB, btab, b1,
                                      nullptr, nullptr, fpad);
        // x = relu(conv(f,w2)+b2+x): f32 + padded bf16 out
        convm_k<3, 42, true, true, true, true, true>
            <<<256, 256, 0, stream>>>(fpad, slab + (2 * r + 1) * SLAB_RB, btab,
                                      b2, ws + OFF_X, ws + OFF_X, xpad);
    }
    // recon: 42 -> 8, f32 out
    convm_k<1, 8, false, false, false, true, false>
        <<<256, 256, 0, stream>>>(xpad, slab + SLAB_RC, btab, nullptr, nullptr,
                                  out, nullptr);
}